// Round 21
// baseline (47.892 us; speedup 1.0000x reference)
//
#include <hip/hip_runtime.h>
#include <hip/hip_bf16.h>

// BatchedNeRFMLP: B=64, N=16384, HID=128, POS_IN=63 (+bias col -> K=64), DIR_IN=27
// params per batch (TOTAL=8789 fp32):
//   pw [128][63] @0   pb[128]@8064   sw[128]@8192  sb@8320
//   cw [3][155] @8321 cb[3]@8786
// out: sigma (B*N) then rgb (B*N*3), fp32.
//
// r20 base (44.6us best) + FLAT ITER BODY at 3 blocks/CU:
//   r16's unroll-1 mt loop won occupancy but walled the dir/encode VALU out
//   of the MFMA shadows (BB-local scheduling). This kernel fully unrolls mt
//   and instead blocks r10's awf-hoist spill with a zero-cost FALSE DEP:
//   asm("" : "+v"(aoff) : "v"(dep)) ties mt+1's LDS-read address to mt's
//   first MFMA result -> reads can't hoist, but dir/encode/prefetch VALU
//   schedule into the MFMA latency shadows (single BB: encode and prefetch
//   made unconditional via index clamp; last-iter re-encode is written-
//   never-read and deterministic).
// Carried: fragment-linear LDS (conflicts 57K) [r19], aw+haw in LDS [r16/r7],
// two nt tiles interleaved [r11], encode writes after all frag reads
// (per-wave DS in-order) [r5], revolution-trig [r9], no setprio [r20].
// Tripwire: VGPR > 84 side / WRITE_SIZE >> 16MB = spill = revert to r20.

#define NB 64
#define NRAY 16384
#define NTOTAL 8789
#define NIT 4

typedef short bf16x8 __attribute__((ext_vector_type(8)));
typedef float f32x16 __attribute__((ext_vector_type(16)));

union U8 { unsigned u[4]; bf16x8 v; };

__device__ __forceinline__ unsigned pk2(float a, float b) {
    float2 t; t.x = a; t.y = b;
    __hip_bfloat162 h = __float22bfloat162_rn(t);   // v_cvt_pk_bf16_f32
    return *reinterpret_cast<unsigned*>(&h);
}

#define MFMA __builtin_amdgcn_mfma_f32_32x32x16_bf16

__global__ __launch_bounds__(256, 3) void nerf_mfma_kernel(
    const float* __restrict__ pos,
    const float* __restrict__ dir,
    const float* __restrict__ params,
    float* __restrict__ out)
{
    const int tid  = threadIdx.x;
    const int lane = tid & 63;
    const int wid  = tid >> 6;
    const int hi   = lane >> 5;
    const int l31  = lane & 31;

    const int b     = blockIdx.x >> 4;          // 16 blocks per batch
    const int chunk = (blockIdx.x & 15) << 10;  // 1024 rays per block
    const float* __restrict__ p = params + b * NTOTAL;

    // fragment-linear tiles: [block][chunk16B]; 1024B per fragment-block
    __shared__ uint4 encs[2048];                // 32 blocks x 64 chunks = 32KB
    __shared__ uint4 awT[1024];                 // 16 blocks x 64 chunks = 16KB
    __shared__ unsigned hawLds[256];            // [s][hi][r][4 words] = 1KB
    char* encb = reinterpret_cast<char*>(encs);
    const char* awb  = reinterpret_cast<const char*>(awT);
    const char* hawb = reinterpret_cast<const char*>(hawLds);

    // ---- head-weight fragments into LDS (one-time, 64 threads) ------------
    // K permuted: slot(s,hh,i) -> h = 32*(s>>1)+16*(s&1)+4*hh+(i&3)+8*(i>>2)
    if (tid < 64) {
        const int s  = tid & 7;
        const int hh = (tid >> 3) & 1;
        const int r  = tid >> 4;                // 0=sigma(sw), 1..3 = cw rows
        const float* w2 = (r == 0) ? (p + 8192) : (p + 8321 + (r - 1) * 155);
        const int base = 32 * (s >> 1) + 16 * (s & 1) + 4 * hh;
        unsigned* dst = &hawLds[(((s << 1) + hh) * 4 + r) * 4];
        #pragma unroll
        for (int jj = 0; jj < 4; ++jj) {
            const int i0 = 2 * jj, i1 = 2 * jj + 1;
            dst[jj] = pk2(w2[base + (i0 & 3) + 8 * (i0 >> 2)],
                          w2[base + (i1 & 3) + 8 * (i1 >> 2)]);
        }
    }

    // ---- layer-1 A tile into LDS, fragment-linear (wave w packs mt=w) ------
    // lane (hi,l31) of fragment (mt,ks): row mt*32+l31, K-order cols
    // k<3 -> pw[row][k]; k==3 -> pb[row]; k>=4 -> pw[row][k-1]
    {
        const int mt = wid;
        const int hrow = mt * 32 + l31;
        const float* wrow = p + hrow * 63;
        const float bias  = p[8064 + hrow];
        char* dst = reinterpret_cast<char*>(awT) + mt * 4096 + lane * 16;
        #pragma unroll
        for (int ks = 0; ks < 4; ++ks) {
            U8 u;
            #pragma unroll
            for (int jj = 0; jj < 4; ++jj) {
                const int k0 = ks * 16 + hi * 8 + 2 * jj;
                const int k1 = k0 + 1;
                const float e0 = (k0 < 3) ? wrow[k0] : (k0 == 3 ? bias : wrow[k0 - 1]);
                const float e1 = (k1 < 3) ? wrow[k1] : (k1 == 3 ? bias : wrow[k1 - 1]);
                u.u[jj] = pk2(e0, e1);
            }
            *reinterpret_cast<uint4*>(dst + ks * 1024) = *reinterpret_cast<uint4*>(&u);
        }
    }

    f32x16 FZ;
    #pragma unroll
    for (int i = 0; i < 16; ++i) FZ[i] = 0.f;

    const float sb  = p[8320];
    const float cb0 = p[8786], cb1 = p[8787], cb2 = p[8788];
    const float* __restrict__ cwr  = p + 8321 + 128;
    const float* __restrict__ cwg  = p + 8321 + 155 + 128;
    const float* __restrict__ cwb2 = p + 8321 + 310 + 128;

    const int rayBlock = b * NRAY + chunk;
    float* __restrict__ rgbout = out + (long)NB * NRAY;
    const long pb0 = (long)(rayBlock + tid) * 3;
    const int hoff = hi * 64 + (l31 & 3) * 16;

    // ---- pos encoding, fragment-linear writes ------------------------------
    auto encode_row = [&](const float3 Pv) {
        char* wbase = encb + ((tid >> 5) * 4) * 1024 + (tid & 31) * 16;
        float s0 = __builtin_amdgcn_sinf(0.5f * Pv.x), c0 = __builtin_amdgcn_cosf(0.5f * Pv.x);
        float s1 = __builtin_amdgcn_sinf(0.5f * Pv.y), c1 = __builtin_amdgcn_cosf(0.5f * Pv.y);
        float s2 = __builtin_amdgcn_sinf(0.5f * Pv.z), c2 = __builtin_amdgcn_cosf(0.5f * Pv.z);
        unsigned wb[4];
        wb[0] = pk2(Pv.x, Pv.y);
        wb[1] = pk2(Pv.z, 1.0f);
        #pragma unroll
        for (int f = 0; f < 10; ++f) {
            const int w = 2 + 3 * f;
            #pragma unroll
            for (int k = 0; k < 3; ++k) {
                const int wk = w + k;
                wb[wk & 3] = (k == 0) ? pk2(s0, s1) : (k == 1) ? pk2(s2, c0) : pk2(c1, c2);
                if ((wk & 3) == 3) {
                    const int g = wk >> 2;
                    uint4 v; v.x = wb[0]; v.y = wb[1]; v.z = wb[2]; v.w = wb[3];
                    *reinterpret_cast<uint4*>(wbase + (g >> 1) * 1024 + (g & 1) * 512) = v;
                }
            }
            if (f < 9) {
                float t;
                t = 2.f * s0 * c0; c0 = fmaf(-2.f * s0, s0, 1.f); s0 = t;
                t = 2.f * s1 * c1; c1 = fmaf(-2.f * s1, s1, 1.f); s1 = t;
                t = 2.f * s2 * c2; c2 = fmaf(-2.f * s2, s2, 1.f); s2 = t;
            }
        }
    };

    // prologue: current inputs + iter-1 prefetch, encode iter-0
    float3 Pc = *reinterpret_cast<const float3*>(pos + pb0);
    float3 Dc = *reinterpret_cast<const float3*>(dir + pb0);
    encode_row(Pc);
    float3 Pn = *reinterpret_cast<const float3*>(pos + pb0 + 768);
    float3 Dn = *reinterpret_cast<const float3*>(dir + pb0 + 768);
    __syncthreads();    // awT + hawLds ready (enc blocks are wave-private)

    #pragma unroll 1
    for (int it = 0; it < NIT; ++it) {
        const int ray = rayBlock + it * 256 + tid;

        // ---- all 8 B-frag reads first, consecutive-address ------------------
        bf16x8 be0[4], be1[4];
        {
            const char* ebase = encb + (wid * 8) * 1024 + lane * 16;
            #pragma unroll
            for (int ks = 0; ks < 4; ++ks) {
                be0[ks] = *reinterpret_cast<const bf16x8*>(ebase + ks * 1024);
                be1[ks] = *reinterpret_cast<const bf16x8*>(ebase + (4 + ks) * 1024);
            }
        }

        // ---- encode(it+1): UNCONDITIONAL (last iter re-encodes, never read);
        //      writes follow all reads in program order (per-wave DS in-order)
        encode_row(Pn);

        // ---- dir-tail partials: independent of MFMA -> schedulable filler ---
        float crd = 0.f, cgd = 0.f, cbd = 0.f;
        {
            float s0 = __builtin_amdgcn_sinf(0.5f * Dc.x), c0 = __builtin_amdgcn_cosf(0.5f * Dc.x);
            float s1 = __builtin_amdgcn_sinf(0.5f * Dc.y), c1 = __builtin_amdgcn_cosf(0.5f * Dc.y);
            float s2 = __builtin_amdgcn_sinf(0.5f * Dc.z), c2 = __builtin_amdgcn_cosf(0.5f * Dc.z);
            crd = fmaf(Dc.x, cwr[0], crd);  cgd = fmaf(Dc.x, cwg[0], cgd);  cbd = fmaf(Dc.x, cwb2[0], cbd);
            crd = fmaf(Dc.y, cwr[1], crd);  cgd = fmaf(Dc.y, cwg[1], cgd);  cbd = fmaf(Dc.y, cwb2[1], cbd);
            crd = fmaf(Dc.z, cwr[2], crd);  cgd = fmaf(Dc.z, cwg[2], cgd);  cbd = fmaf(Dc.z, cwb2[2], cbd);
            #pragma unroll
            for (int f = 0; f < 4; ++f) {
                const int jj = 3 + 6 * f;
                crd = fmaf(s0, cwr[jj+0], crd); cgd = fmaf(s0, cwg[jj+0], cgd); cbd = fmaf(s0, cwb2[jj+0], cbd);
                crd = fmaf(s1, cwr[jj+1], crd); cgd = fmaf(s1, cwg[jj+1], cgd); cbd = fmaf(s1, cwb2[jj+1], cbd);
                crd = fmaf(s2, cwr[jj+2], crd); cgd = fmaf(s2, cwg[jj+2], cgd); cbd = fmaf(s2, cwb2[jj+2], cbd);
                crd = fmaf(c0, cwr[jj+3], crd); cgd = fmaf(c0, cwg[jj+3], cgd); cbd = fmaf(c0, cwb2[jj+3], cbd);
                crd = fmaf(c1, cwr[jj+4], crd); cgd = fmaf(c1, cwg[jj+4], cgd); cbd = fmaf(c1, cwb2[jj+4], cbd);
                crd = fmaf(c2, cwr[jj+5], crd); cgd = fmaf(c2, cwg[jj+5], cgd); cbd = fmaf(c2, cwb2[jj+5], cbd);
                if (f < 3) {
                    float t;
                    t = 2.f * s0 * c0; c0 = fmaf(-2.f * s0, s0, 1.f); s0 = t;
                    t = 2.f * s1 * c1; c1 = fmaf(-2.f * s1, s1, 1.f); s1 = t;
                    t = 2.f * s2 * c2; c2 = fmaf(-2.f * s2, s2, 1.f); s2 = t;
                }
            }
        }

        // ---- prefetch (it+2, clamped -> unconditional, schedulable) ---------
        const int nidx = (it + 2 < NIT) ? (it + 2) : (NIT - 1);
        float3 Pn2 = *reinterpret_cast<const float3*>(pos + pb0 + nidx * 768);
        float3 Dn2 = *reinterpret_cast<const float3*>(dir + pb0 + nidx * 768);

        // ---- MFMA region: FULLY UNROLLED, awf hoist blocked by false dep ----
        f32x16 hacc0, hacc1;
        float dep = 0.f;
        #pragma unroll
        for (int mt = 0; mt < 4; ++mt) {
            unsigned aoff = (unsigned)(mt * 4096) + (unsigned)(lane * 16);
            if (mt > 0) asm("" : "+v"(aoff) : "v"(dep));  // no code; order only
            const char* abase = awb + aoff;
            const bf16x8 awf0 = *reinterpret_cast<const bf16x8*>(abase);
            const bf16x8 awf1 = *reinterpret_cast<const bf16x8*>(abase + 1024);
            const bf16x8 awf2 = *reinterpret_cast<const bf16x8*>(abase + 2048);
            const bf16x8 awf3 = *reinterpret_cast<const bf16x8*>(abase + 3072);

            f32x16 a0 = MFMA(awf0, be0[0], FZ, 0, 0, 0);
            f32x16 a1 = MFMA(awf0, be1[0], FZ, 0, 0, 0);
            if (mt < 3) dep = a0[0];      // dep ready after mt's first MFMA
            a0 = MFMA(awf1, be0[1], a0, 0, 0, 0);
            a1 = MFMA(awf1, be1[1], a1, 0, 0, 0);
            a0 = MFMA(awf2, be0[2], a0, 0, 0, 0);
            a1 = MFMA(awf2, be1[2], a1, 0, 0, 0);
            a0 = MFMA(awf3, be0[3], a0, 0, 0, 0);
            a1 = MFMA(awf3, be1[3], a1, 0, 0, 0);

            // relu -> pack own regs (pi-permuted head K: no cross-lane moves)
            #pragma unroll
            for (int t = 0; t < 2; ++t) {
                const int rb = t * 8;
                const int s = 2 * mt + t;
                U8 u0, u1;
                #pragma unroll
                for (int jj = 0; jj < 4; ++jj) {
                    u0.u[jj] = pk2(fmaxf(a0[rb + 2 * jj], 0.f),
                                   fmaxf(a0[rb + 2 * jj + 1], 0.f));
                    u1.u[jj] = pk2(fmaxf(a1[rb + 2 * jj], 0.f),
                                   fmaxf(a1[rb + 2 * jj + 1], 0.f));
                }
                const bf16x8 hw = *reinterpret_cast<const bf16x8*>(
                    hawb + s * 128 + hoff);
                hacc0 = MFMA(hw, u0.v, (s == 0) ? FZ : hacc0, 0, 0, 0);
                hacc1 = MFMA(hw, u1.v, (s == 0) ? FZ : hacc1, 0, 0, 0);
            }
        }

        // ---- per-ray tail: select + bias + dir partial + sigmoid -----------
        const float hv0 = hi ? hacc1[0] : hacc0[0];
        const float hv1 = hi ? hacc1[1] : hacc0[1];
        const float hv2 = hi ? hacc1[2] : hacc0[2];
        const float hv3 = hi ? hacc1[3] : hacc0[3];

        const float sig = hv0 + sb;
        float cr  = hv1 + cb0 + crd;
        float cg  = hv2 + cb1 + cgd;
        float cbl = hv3 + cb2 + cbd;

        cr  = 1.0f / (1.0f + __expf(-cr));
        cg  = 1.0f / (1.0f + __expf(-cg));
        cbl = 1.0f / (1.0f + __expf(-cbl));

        out[ray] = sig;
        float3 rgbv; rgbv.x = cr; rgbv.y = cg; rgbv.z = cbl;
        *reinterpret_cast<float3*>(rgbout + (long)ray * 3) = rgbv;

        Pn = Pn2; Dc = Dn; Dn = Dn2;
    }
}

extern "C" void kernel_launch(void* const* d_in, const int* in_sizes, int n_in,
                              void* d_out, int out_size, void* d_ws, size_t ws_size,
                              hipStream_t stream) {
    const float* pos    = (const float*)d_in[0];
    const float* dirs   = (const float*)d_in[1];
    const float* params = (const float*)d_in[2];
    float* out = (float*)d_out;

    dim3 grid(1024);   // 16 blocks/batch x 64 batches, 1024 rays each
    dim3 block(256);
    nerf_mfma_kernel<<<grid, block, 0, stream>>>(pos, dirs, params, out);
}

// Round 22
// 45.756 us; speedup vs baseline: 1.0467x; 1.0467x over previous
//
#include <hip/hip_runtime.h>
#include <hip/hip_bf16.h>

// BatchedNeRFMLP: B=64, N=16384, HID=128, POS_IN=63 (+bias col -> K=64), DIR_IN=27
// params per batch (TOTAL=8789 fp32):
//   pw [128][63] @0   pb[128]@8064   sw[128]@8192  sb@8320
//   cw [3][155] @8321 cb[3]@8786
// out: sigma (B*N) then rgb (B*N*3), fp32.
//
// r20 base (44.6us best) + ONLY the mt-unroll+false-dep from r21:
//   r21 isolated-fail: unconditional encode + clamped prefetch extended live
//   ranges across the MFMA region (+16 arch regs -> 84 cap -> mild spill,
//   WRITE 24MB). This round keeps encode/prefetch CONDITIONAL (r20 form, live
//   state dies before MFMA region) and keeps the mt loop FULLY UNROLLED with
//   the zero-cost false dep asm("":"+v"(aoff):"v"(dep)) that stops awf-read
//   hoisting (r10's spill mode) while letting the dir-tail VALU schedule into
//   the MFMA latency shadows (r15: compiler does this in flat bodies).
// Carried: fragment-linear LDS (conflicts 57K) [r19], aw+haw in LDS [r16/r7],
// two nt tiles interleaved [r11], encode writes after all frag reads
// (per-wave DS in-order) [r5], revolution-trig [r9], no setprio [r20].
// Tripwire: VGPR >= 84 / WRITE >> 16MB = spill = r20 is final.

#define NB 64
#define NRAY 16384
#define NTOTAL 8789
#define NIT 4

typedef short bf16x8 __attribute__((ext_vector_type(8)));
typedef float f32x16 __attribute__((ext_vector_type(16)));

union U8 { unsigned u[4]; bf16x8 v; };

__device__ __forceinline__ unsigned pk2(float a, float b) {
    float2 t; t.x = a; t.y = b;
    __hip_bfloat162 h = __float22bfloat162_rn(t);   // v_cvt_pk_bf16_f32
    return *reinterpret_cast<unsigned*>(&h);
}

#define MFMA __builtin_amdgcn_mfma_f32_32x32x16_bf16

__global__ __launch_bounds__(256, 3) void nerf_mfma_kernel(
    const float* __restrict__ pos,
    const float* __restrict__ dir,
    const float* __restrict__ params,
    float* __restrict__ out)
{
    const int tid  = threadIdx.x;
    const int lane = tid & 63;
    const int wid  = tid >> 6;
    const int hi   = lane >> 5;
    const int l31  = lane & 31;

    const int b     = blockIdx.x >> 4;          // 16 blocks per batch
    const int chunk = (blockIdx.x & 15) << 10;  // 1024 rays per block
    const float* __restrict__ p = params + b * NTOTAL;

    // fragment-linear tiles: [block][chunk16B]; 1024B per fragment-block
    __shared__ uint4 encs[2048];                // 32 blocks x 64 chunks = 32KB
    __shared__ uint4 awT[1024];                 // 16 blocks x 64 chunks = 16KB
    __shared__ unsigned hawLds[256];            // [s][hi][r][4 words] = 1KB
    char* encb = reinterpret_cast<char*>(encs);
    const char* awb  = reinterpret_cast<const char*>(awT);
    const char* hawb = reinterpret_cast<const char*>(hawLds);

    // ---- head-weight fragments into LDS (one-time, 64 threads) ------------
    // K permuted: slot(s,hh,i) -> h = 32*(s>>1)+16*(s&1)+4*hh+(i&3)+8*(i>>2)
    if (tid < 64) {
        const int s  = tid & 7;
        const int hh = (tid >> 3) & 1;
        const int r  = tid >> 4;                // 0=sigma(sw), 1..3 = cw rows
        const float* w2 = (r == 0) ? (p + 8192) : (p + 8321 + (r - 1) * 155);
        const int base = 32 * (s >> 1) + 16 * (s & 1) + 4 * hh;
        unsigned* dst = &hawLds[(((s << 1) + hh) * 4 + r) * 4];
        #pragma unroll
        for (int jj = 0; jj < 4; ++jj) {
            const int i0 = 2 * jj, i1 = 2 * jj + 1;
            dst[jj] = pk2(w2[base + (i0 & 3) + 8 * (i0 >> 2)],
                          w2[base + (i1 & 3) + 8 * (i1 >> 2)]);
        }
    }

    // ---- layer-1 A tile into LDS, fragment-linear (wave w packs mt=w) ------
    // lane (hi,l31) of fragment (mt,ks): row mt*32+l31, K-order cols
    // k<3 -> pw[row][k]; k==3 -> pb[row]; k>=4 -> pw[row][k-1]
    {
        const int mt = wid;
        const int hrow = mt * 32 + l31;
        const float* wrow = p + hrow * 63;
        const float bias  = p[8064 + hrow];
        char* dst = reinterpret_cast<char*>(awT) + mt * 4096 + lane * 16;
        #pragma unroll
        for (int ks = 0; ks < 4; ++ks) {
            U8 u;
            #pragma unroll
            for (int jj = 0; jj < 4; ++jj) {
                const int k0 = ks * 16 + hi * 8 + 2 * jj;
                const int k1 = k0 + 1;
                const float e0 = (k0 < 3) ? wrow[k0] : (k0 == 3 ? bias : wrow[k0 - 1]);
                const float e1 = (k1 < 3) ? wrow[k1] : (k1 == 3 ? bias : wrow[k1 - 1]);
                u.u[jj] = pk2(e0, e1);
            }
            *reinterpret_cast<uint4*>(dst + ks * 1024) = *reinterpret_cast<uint4*>(&u);
        }
    }

    f32x16 FZ;
    #pragma unroll
    for (int i = 0; i < 16; ++i) FZ[i] = 0.f;

    const float sb  = p[8320];
    const float cb0 = p[8786], cb1 = p[8787], cb2 = p[8788];
    const float* __restrict__ cwr  = p + 8321 + 128;
    const float* __restrict__ cwg  = p + 8321 + 155 + 128;
    const float* __restrict__ cwb2 = p + 8321 + 310 + 128;

    const int rayBlock = b * NRAY + chunk;
    float* __restrict__ rgbout = out + (long)NB * NRAY;
    const long pb0 = (long)(rayBlock + tid) * 3;
    const int hoff = hi * 64 + (l31 & 3) * 16;

    // ---- pos encoding, fragment-linear writes ------------------------------
    auto encode_row = [&](const float3 Pv) {
        char* wbase = encb + ((tid >> 5) * 4) * 1024 + (tid & 31) * 16;
        float s0 = __builtin_amdgcn_sinf(0.5f * Pv.x), c0 = __builtin_amdgcn_cosf(0.5f * Pv.x);
        float s1 = __builtin_amdgcn_sinf(0.5f * Pv.y), c1 = __builtin_amdgcn_cosf(0.5f * Pv.y);
        float s2 = __builtin_amdgcn_sinf(0.5f * Pv.z), c2 = __builtin_amdgcn_cosf(0.5f * Pv.z);
        unsigned wb[4];
        wb[0] = pk2(Pv.x, Pv.y);
        wb[1] = pk2(Pv.z, 1.0f);
        #pragma unroll
        for (int f = 0; f < 10; ++f) {
            const int w = 2 + 3 * f;
            #pragma unroll
            for (int k = 0; k < 3; ++k) {
                const int wk = w + k;
                wb[wk & 3] = (k == 0) ? pk2(s0, s1) : (k == 1) ? pk2(s2, c0) : pk2(c1, c2);
                if ((wk & 3) == 3) {
                    const int g = wk >> 2;
                    uint4 v; v.x = wb[0]; v.y = wb[1]; v.z = wb[2]; v.w = wb[3];
                    *reinterpret_cast<uint4*>(wbase + (g >> 1) * 1024 + (g & 1) * 512) = v;
                }
            }
            if (f < 9) {
                float t;
                t = 2.f * s0 * c0; c0 = fmaf(-2.f * s0, s0, 1.f); s0 = t;
                t = 2.f * s1 * c1; c1 = fmaf(-2.f * s1, s1, 1.f); s1 = t;
                t = 2.f * s2 * c2; c2 = fmaf(-2.f * s2, s2, 1.f); s2 = t;
            }
        }
    };

    // prologue: current inputs + iter-1 prefetch, encode iter-0
    float3 Pc = *reinterpret_cast<const float3*>(pos + pb0);
    float3 Dc = *reinterpret_cast<const float3*>(dir + pb0);
    encode_row(Pc);
    float3 Pn = *reinterpret_cast<const float3*>(pos + pb0 + 768);
    float3 Dn = *reinterpret_cast<const float3*>(dir + pb0 + 768);
    __syncthreads();    // awT + hawLds ready (enc blocks are wave-private)

    #pragma unroll 1
    for (int it = 0; it < NIT; ++it) {
        const int ray = rayBlock + it * 256 + tid;

        // ---- all 8 B-frag reads first, consecutive-address ------------------
        bf16x8 be0[4], be1[4];
        {
            const char* ebase = encb + (wid * 8) * 1024 + lane * 16;
            #pragma unroll
            for (int ks = 0; ks < 4; ++ks) {
                be0[ks] = *reinterpret_cast<const bf16x8*>(ebase + ks * 1024);
                be1[ks] = *reinterpret_cast<const bf16x8*>(ebase + (4 + ks) * 1024);
            }
        }

        // ---- encode(it+1): CONDITIONAL (state dies before MFMA region);
        //      writes follow all reads in program order (per-wave DS in-order)
        if (it < NIT - 1) encode_row(Pn);

        // ---- dir-tail partials: independent of MFMA -> schedulable filler ---
        float crd = 0.f, cgd = 0.f, cbd = 0.f;
        {
            float s0 = __builtin_amdgcn_sinf(0.5f * Dc.x), c0 = __builtin_amdgcn_cosf(0.5f * Dc.x);
            float s1 = __builtin_amdgcn_sinf(0.5f * Dc.y), c1 = __builtin_amdgcn_cosf(0.5f * Dc.y);
            float s2 = __builtin_amdgcn_sinf(0.5f * Dc.z), c2 = __builtin_amdgcn_cosf(0.5f * Dc.z);
            crd = fmaf(Dc.x, cwr[0], crd);  cgd = fmaf(Dc.x, cwg[0], cgd);  cbd = fmaf(Dc.x, cwb2[0], cbd);
            crd = fmaf(Dc.y, cwr[1], crd);  cgd = fmaf(Dc.y, cwg[1], cgd);  cbd = fmaf(Dc.y, cwb2[1], cbd);
            crd = fmaf(Dc.z, cwr[2], crd);  cgd = fmaf(Dc.z, cwg[2], cgd);  cbd = fmaf(Dc.z, cwb2[2], cbd);
            #pragma unroll
            for (int f = 0; f < 4; ++f) {
                const int jj = 3 + 6 * f;
                crd = fmaf(s0, cwr[jj+0], crd); cgd = fmaf(s0, cwg[jj+0], cgd); cbd = fmaf(s0, cwb2[jj+0], cbd);
                crd = fmaf(s1, cwr[jj+1], crd); cgd = fmaf(s1, cwg[jj+1], cgd); cbd = fmaf(s1, cwb2[jj+1], cbd);
                crd = fmaf(s2, cwr[jj+2], crd); cgd = fmaf(s2, cwg[jj+2], cgd); cbd = fmaf(s2, cwb2[jj+2], cbd);
                crd = fmaf(c0, cwr[jj+3], crd); cgd = fmaf(c0, cwg[jj+3], cgd); cbd = fmaf(c0, cwb2[jj+3], cbd);
                crd = fmaf(c1, cwr[jj+4], crd); cgd = fmaf(c1, cwg[jj+4], cgd); cbd = fmaf(c1, cwb2[jj+4], cbd);
                crd = fmaf(c2, cwr[jj+5], crd); cgd = fmaf(c2, cwg[jj+5], cgd); cbd = fmaf(c2, cwb2[jj+5], cbd);
                if (f < 3) {
                    float t;
                    t = 2.f * s0 * c0; c0 = fmaf(-2.f * s0, s0, 1.f); s0 = t;
                    t = 2.f * s1 * c1; c1 = fmaf(-2.f * s1, s1, 1.f); s1 = t;
                    t = 2.f * s2 * c2; c2 = fmaf(-2.f * s2, s2, 1.f); s2 = t;
                }
            }
        }

        // ---- prefetch (it+2): CONDITIONAL (r20 form) ------------------------
        float3 Pn2, Dn2;
        if (it < NIT - 2) {
            Pn2 = *reinterpret_cast<const float3*>(pos + pb0 + (it + 2) * 768);
            Dn2 = *reinterpret_cast<const float3*>(dir + pb0 + (it + 2) * 768);
        }

        // ---- MFMA region: FULLY UNROLLED, awf hoist blocked by false dep ----
        f32x16 hacc0, hacc1;
        float dep = 0.f;
        #pragma unroll
        for (int mt = 0; mt < 4; ++mt) {
            unsigned aoff = (unsigned)(mt * 4096) + (unsigned)(lane * 16);
            if (mt > 0) asm("" : "+v"(aoff) : "v"(dep));  // no code; order only
            const char* abase = awb + aoff;
            const bf16x8 awf0 = *reinterpret_cast<const bf16x8*>(abase);
            const bf16x8 awf1 = *reinterpret_cast<const bf16x8*>(abase + 1024);
            const bf16x8 awf2 = *reinterpret_cast<const bf16x8*>(abase + 2048);
            const bf16x8 awf3 = *reinterpret_cast<const bf16x8*>(abase + 3072);

            f32x16 a0 = MFMA(awf0, be0[0], FZ, 0, 0, 0);
            f32x16 a1 = MFMA(awf0, be1[0], FZ, 0, 0, 0);
            if (mt < 3) dep = a0[0];      // dep ready after mt's first MFMA
            a0 = MFMA(awf1, be0[1], a0, 0, 0, 0);
            a1 = MFMA(awf1, be1[1], a1, 0, 0, 0);
            a0 = MFMA(awf2, be0[2], a0, 0, 0, 0);
            a1 = MFMA(awf2, be1[2], a1, 0, 0, 0);
            a0 = MFMA(awf3, be0[3], a0, 0, 0, 0);
            a1 = MFMA(awf3, be1[3], a1, 0, 0, 0);

            // relu -> pack own regs (pi-permuted head K: no cross-lane moves)
            #pragma unroll
            for (int t = 0; t < 2; ++t) {
                const int rb = t * 8;
                const int s = 2 * mt + t;
                U8 u0, u1;
                #pragma unroll
                for (int jj = 0; jj < 4; ++jj) {
                    u0.u[jj] = pk2(fmaxf(a0[rb + 2 * jj], 0.f),
                                   fmaxf(a0[rb + 2 * jj + 1], 0.f));
                    u1.u[jj] = pk2(fmaxf(a1[rb + 2 * jj], 0.f),
                                   fmaxf(a1[rb + 2 * jj + 1], 0.f));
                }
                const bf16x8 hw = *reinterpret_cast<const bf16x8*>(
                    hawb + s * 128 + hoff);
                hacc0 = MFMA(hw, u0.v, (s == 0) ? FZ : hacc0, 0, 0, 0);
                hacc1 = MFMA(hw, u1.v, (s == 0) ? FZ : hacc1, 0, 0, 0);
            }
        }

        // ---- per-ray tail: select + bias + dir partial + sigmoid -----------
        const float hv0 = hi ? hacc1[0] : hacc0[0];
        const float hv1 = hi ? hacc1[1] : hacc0[1];
        const float hv2 = hi ? hacc1[2] : hacc0[2];
        const float hv3 = hi ? hacc1[3] : hacc0[3];

        const float sig = hv0 + sb;
        float cr  = hv1 + cb0 + crd;
        float cg  = hv2 + cb1 + cgd;
        float cbl = hv3 + cb2 + cbd;

        cr  = 1.0f / (1.0f + __expf(-cr));
        cg  = 1.0f / (1.0f + __expf(-cg));
        cbl = 1.0f / (1.0f + __expf(-cbl));

        out[ray] = sig;
        float3 rgbv; rgbv.x = cr; rgbv.y = cg; rgbv.z = cbl;
        *reinterpret_cast<float3*>(rgbout + (long)ray * 3) = rgbv;

        Pn = Pn2; Dc = Dn; Dn = Dn2;
    }
}

extern "C" void kernel_launch(void* const* d_in, const int* in_sizes, int n_in,
                              void* d_out, int out_size, void* d_ws, size_t ws_size,
                              hipStream_t stream) {
    const float* pos    = (const float*)d_in[0];
    const float* dirs   = (const float*)d_in[1];
    const float* params = (const float*)d_in[2];
    float* out = (float*)d_out;

    dim3 grid(1024);   // 16 blocks/batch x 64 batches, 1024 rays each
    dim3 block(256);
    nerf_mfma_kernel<<<grid, block, 0, stream>>>(pos, dirs, params, out);
}

// Round 23
// 43.951 us; speedup vs baseline: 1.0897x; 1.0411x over previous
//
#include <hip/hip_runtime.h>
#include <hip/hip_bf16.h>

// BatchedNeRFMLP: B=64, N=16384, HID=128, POS_IN=63 (+bias col -> K=64), DIR_IN=27
// params per batch (TOTAL=8789 fp32):
//   pw [128][63] @0   pb[128]@8064   sw[128]@8192  sb@8320
//   cw [3][155] @8321 cb[3]@8786
// out: sigma (B*N) then rgb (B*N*3), fp32.
//
// r20 base (44.6us best, VGPR 68, no spill) + T1 XCD-AWARE BLOCK SWIZZLE:
//   default dispatch puts batch b's 16 blocks on all 8 XCDs -> each XCD's L2
//   refetches b's 35KB params (FETCH 21MB vs 2.25MB unique). Remap
//   b=(d&7)*8+((d>>3)&7), chunk=d>>6 (bijective; XCD = d%8 approx) so all 16
//   blocks of a batch land on one XCD; 8 batches x 35KB = 280KB << 4MB L2.
//   Prologue param reads become L2 hits (~200 vs ~900 cyc).
// Carried from r20/r19/r16:
//   - fragment-linear LDS (conflicts 57K): block[frag]*1024+lane*16   [r19]
//   - 3 blocks/CU via aw-in-LDS + mt unroll-1 (awf 16 regs live)      [r16]
//   - two nt tiles interleaved (2 independent L1 MFMA chains)         [r11]
//   - haw in LDS (1KB, broadcast reads)                               [r7]
//   - encode(it+1) after all frag reads (per-wave DS in-order)        [r5]
//   - dir-tail VALU before MFMA region                                [r11]
//   - revolution-trig: sin(pi x) = builtin_sinf(0.5x)                 [r9]
//   - no setprio (neutral, r20); flat-body/mt-unroll rejected (r21/r22 spill)
// Tripwire: WRITE_SIZE >> 16MB = spill = revert.

#define NB 64
#define NRAY 16384
#define NTOTAL 8789
#define NIT 4

typedef short bf16x8 __attribute__((ext_vector_type(8)));
typedef float f32x16 __attribute__((ext_vector_type(16)));

union U8 { unsigned u[4]; bf16x8 v; };

__device__ __forceinline__ unsigned pk2(float a, float b) {
    float2 t; t.x = a; t.y = b;
    __hip_bfloat162 h = __float22bfloat162_rn(t);   // v_cvt_pk_bf16_f32
    return *reinterpret_cast<unsigned*>(&h);
}

#define MFMA __builtin_amdgcn_mfma_f32_32x32x16_bf16

__global__ __launch_bounds__(256, 3) void nerf_mfma_kernel(
    const float* __restrict__ pos,
    const float* __restrict__ dir,
    const float* __restrict__ params,
    float* __restrict__ out)
{
    const int tid  = threadIdx.x;
    const int lane = tid & 63;
    const int wid  = tid >> 6;
    const int hi   = lane >> 5;
    const int l31  = lane & 31;

    // XCD-aware swizzle: XCD ~= d%8; all 16 blocks of batch b share XCD b>>3
    const int d     = blockIdx.x;
    const int b     = (d & 7) * 8 + ((d >> 3) & 7);
    const int chunk = (d >> 6) << 10;           // 16 chunks x 1024 rays
    const float* __restrict__ p = params + b * NTOTAL;

    // fragment-linear tiles: [block][chunk16B]; 1024B per fragment-block
    __shared__ uint4 encs[2048];                // 32 blocks x 64 chunks = 32KB
    __shared__ uint4 awT[1024];                 // 16 blocks x 64 chunks = 16KB
    __shared__ unsigned hawLds[256];            // [s][hi][r][4 words] = 1KB
    char* encb = reinterpret_cast<char*>(encs);
    const char* awb  = reinterpret_cast<const char*>(awT);
    const char* hawb = reinterpret_cast<const char*>(hawLds);

    // ---- head-weight fragments into LDS (one-time, 64 threads) ------------
    // K permuted: slot(s,hh,i) -> h = 32*(s>>1)+16*(s&1)+4*hh+(i&3)+8*(i>>2)
    if (tid < 64) {
        const int s  = tid & 7;
        const int hh = (tid >> 3) & 1;
        const int r  = tid >> 4;                // 0=sigma(sw), 1..3 = cw rows
        const float* w2 = (r == 0) ? (p + 8192) : (p + 8321 + (r - 1) * 155);
        const int base = 32 * (s >> 1) + 16 * (s & 1) + 4 * hh;
        unsigned* dst = &hawLds[(((s << 1) + hh) * 4 + r) * 4];
        #pragma unroll
        for (int jj = 0; jj < 4; ++jj) {
            const int i0 = 2 * jj, i1 = 2 * jj + 1;
            dst[jj] = pk2(w2[base + (i0 & 3) + 8 * (i0 >> 2)],
                          w2[base + (i1 & 3) + 8 * (i1 >> 2)]);
        }
    }

    // ---- layer-1 A tile into LDS, fragment-linear (wave w packs mt=w) ------
    // lane (hi,l31) of fragment (mt,ks): row mt*32+l31, K-order cols
    // k<3 -> pw[row][k]; k==3 -> pb[row]; k>=4 -> pw[row][k-1]
    {
        const int mt = wid;
        const int hrow = mt * 32 + l31;
        const float* wrow = p + hrow * 63;
        const float bias  = p[8064 + hrow];
        char* dst = reinterpret_cast<char*>(awT) + mt * 4096 + lane * 16;
        #pragma unroll
        for (int ks = 0; ks < 4; ++ks) {
            U8 u;
            #pragma unroll
            for (int jj = 0; jj < 4; ++jj) {
                const int k0 = ks * 16 + hi * 8 + 2 * jj;
                const int k1 = k0 + 1;
                const float e0 = (k0 < 3) ? wrow[k0] : (k0 == 3 ? bias : wrow[k0 - 1]);
                const float e1 = (k1 < 3) ? wrow[k1] : (k1 == 3 ? bias : wrow[k1 - 1]);
                u.u[jj] = pk2(e0, e1);
            }
            *reinterpret_cast<uint4*>(dst + ks * 1024) = *reinterpret_cast<uint4*>(&u);
        }
    }

    f32x16 FZ;
    #pragma unroll
    for (int i = 0; i < 16; ++i) FZ[i] = 0.f;

    const float sb  = p[8320];
    const float cb0 = p[8786], cb1 = p[8787], cb2 = p[8788];
    const float* __restrict__ cwr  = p + 8321 + 128;
    const float* __restrict__ cwg  = p + 8321 + 155 + 128;
    const float* __restrict__ cwb2 = p + 8321 + 310 + 128;

    const int rayBlock = b * NRAY + chunk;
    float* __restrict__ rgbout = out + (long)NB * NRAY;
    const long pb0 = (long)(rayBlock + tid) * 3;
    const int hoff = hi * 64 + (l31 & 3) * 16;

    // ---- pos encoding, fragment-linear writes ------------------------------
    auto encode_row = [&](const float3 Pv) {
        char* wbase = encb + ((tid >> 5) * 4) * 1024 + (tid & 31) * 16;
        float s0 = __builtin_amdgcn_sinf(0.5f * Pv.x), c0 = __builtin_amdgcn_cosf(0.5f * Pv.x);
        float s1 = __builtin_amdgcn_sinf(0.5f * Pv.y), c1 = __builtin_amdgcn_cosf(0.5f * Pv.y);
        float s2 = __builtin_amdgcn_sinf(0.5f * Pv.z), c2 = __builtin_amdgcn_cosf(0.5f * Pv.z);
        unsigned wb[4];
        wb[0] = pk2(Pv.x, Pv.y);
        wb[1] = pk2(Pv.z, 1.0f);
        #pragma unroll
        for (int f = 0; f < 10; ++f) {
            const int w = 2 + 3 * f;
            #pragma unroll
            for (int k = 0; k < 3; ++k) {
                const int wk = w + k;
                wb[wk & 3] = (k == 0) ? pk2(s0, s1) : (k == 1) ? pk2(s2, c0) : pk2(c1, c2);
                if ((wk & 3) == 3) {
                    const int g = wk >> 2;
                    uint4 v; v.x = wb[0]; v.y = wb[1]; v.z = wb[2]; v.w = wb[3];
                    *reinterpret_cast<uint4*>(wbase + (g >> 1) * 1024 + (g & 1) * 512) = v;
                }
            }
            if (f < 9) {
                float t;
                t = 2.f * s0 * c0; c0 = fmaf(-2.f * s0, s0, 1.f); s0 = t;
                t = 2.f * s1 * c1; c1 = fmaf(-2.f * s1, s1, 1.f); s1 = t;
                t = 2.f * s2 * c2; c2 = fmaf(-2.f * s2, s2, 1.f); s2 = t;
            }
        }
    };

    // prologue: current inputs + iter-1 prefetch, encode iter-0
    float3 Pc = *reinterpret_cast<const float3*>(pos + pb0);
    float3 Dc = *reinterpret_cast<const float3*>(dir + pb0);
    encode_row(Pc);
    float3 Pn = *reinterpret_cast<const float3*>(pos + pb0 + 768);
    float3 Dn = *reinterpret_cast<const float3*>(dir + pb0 + 768);
    __syncthreads();    // awT + hawLds ready (enc blocks are wave-private)

    #pragma unroll 1
    for (int it = 0; it < NIT; ++it) {
        const int ray = rayBlock + it * 256 + tid;

        // ---- all 8 B-frag reads first, consecutive-address ------------------
        bf16x8 be0[4], be1[4];
        {
            const char* ebase = encb + (wid * 8) * 1024 + lane * 16;
            #pragma unroll
            for (int ks = 0; ks < 4; ++ks) {
                be0[ks] = *reinterpret_cast<const bf16x8*>(ebase + ks * 1024);
                be1[ks] = *reinterpret_cast<const bf16x8*>(ebase + (4 + ks) * 1024);
            }
        }

        // ---- encode(it+1): writes after reads (per-wave DS in-order) -------
        if (it < NIT - 1) encode_row(Pn);

        // ---- dir-tail partials: independent of MFMA -> latency filler ------
        float crd = 0.f, cgd = 0.f, cbd = 0.f;
        {
            float s0 = __builtin_amdgcn_sinf(0.5f * Dc.x), c0 = __builtin_amdgcn_cosf(0.5f * Dc.x);
            float s1 = __builtin_amdgcn_sinf(0.5f * Dc.y), c1 = __builtin_amdgcn_cosf(0.5f * Dc.y);
            float s2 = __builtin_amdgcn_sinf(0.5f * Dc.z), c2 = __builtin_amdgcn_cosf(0.5f * Dc.z);
            crd = fmaf(Dc.x, cwr[0], crd);  cgd = fmaf(Dc.x, cwg[0], cgd);  cbd = fmaf(Dc.x, cwb2[0], cbd);
            crd = fmaf(Dc.y, cwr[1], crd);  cgd = fmaf(Dc.y, cwg[1], cgd);  cbd = fmaf(Dc.y, cwb2[1], cbd);
            crd = fmaf(Dc.z, cwr[2], crd);  cgd = fmaf(Dc.z, cwg[2], cgd);  cbd = fmaf(Dc.z, cwb2[2], cbd);
            #pragma unroll
            for (int f = 0; f < 4; ++f) {
                const int jj = 3 + 6 * f;
                crd = fmaf(s0, cwr[jj+0], crd); cgd = fmaf(s0, cwg[jj+0], cgd); cbd = fmaf(s0, cwb2[jj+0], cbd);
                crd = fmaf(s1, cwr[jj+1], crd); cgd = fmaf(s1, cwg[jj+1], cgd); cbd = fmaf(s1, cwb2[jj+1], cbd);
                crd = fmaf(s2, cwr[jj+2], crd); cgd = fmaf(s2, cwg[jj+2], cgd); cbd = fmaf(s2, cwb2[jj+2], cbd);
                crd = fmaf(c0, cwr[jj+3], crd); cgd = fmaf(c0, cwg[jj+3], cgd); cbd = fmaf(c0, cwb2[jj+3], cbd);
                crd = fmaf(c1, cwr[jj+4], crd); cgd = fmaf(c1, cwg[jj+4], cgd); cbd = fmaf(c1, cwb2[jj+4], cbd);
                crd = fmaf(c2, cwr[jj+5], crd); cgd = fmaf(c2, cwg[jj+5], cgd); cbd = fmaf(c2, cwb2[jj+5], cbd);
                if (f < 3) {
                    float t;
                    t = 2.f * s0 * c0; c0 = fmaf(-2.f * s0, s0, 1.f); s0 = t;
                    t = 2.f * s1 * c1; c1 = fmaf(-2.f * s1, s1, 1.f); s1 = t;
                    t = 2.f * s2 * c2; c2 = fmaf(-2.f * s2, s2, 1.f); s2 = t;
                }
            }
        }

        // ---- prefetch inputs for it+2 (rotate below) ------------------------
        float3 Pn2, Dn2;
        if (it < NIT - 2) {
            Pn2 = *reinterpret_cast<const float3*>(pos + pb0 + (it + 2) * 768);
            Dn2 = *reinterpret_cast<const float3*>(dir + pb0 + (it + 2) * 768);
        }

        // ---- MFMA region: mt loop NOT unrolled (awf stays 16 regs) ---------
        f32x16 hacc0 = FZ, hacc1 = FZ;
        #pragma unroll 1
        for (int mt = 0; mt < 4; ++mt) {
            const char* abase = awb + mt * 4096 + lane * 16;
            const bf16x8 awf0 = *reinterpret_cast<const bf16x8*>(abase);
            const bf16x8 awf1 = *reinterpret_cast<const bf16x8*>(abase + 1024);
            const bf16x8 awf2 = *reinterpret_cast<const bf16x8*>(abase + 2048);
            const bf16x8 awf3 = *reinterpret_cast<const bf16x8*>(abase + 3072);

            f32x16 a0 = MFMA(awf0, be0[0], FZ, 0, 0, 0);
            f32x16 a1 = MFMA(awf0, be1[0], FZ, 0, 0, 0);
            a0 = MFMA(awf1, be0[1], a0, 0, 0, 0);
            a1 = MFMA(awf1, be1[1], a1, 0, 0, 0);
            a0 = MFMA(awf2, be0[2], a0, 0, 0, 0);
            a1 = MFMA(awf2, be1[2], a1, 0, 0, 0);
            a0 = MFMA(awf3, be0[3], a0, 0, 0, 0);
            a1 = MFMA(awf3, be1[3], a1, 0, 0, 0);

            // relu -> pack own regs (pi-permuted head K: no cross-lane moves)
            #pragma unroll
            for (int t = 0; t < 2; ++t) {
                const int rb = t * 8;
                U8 u0, u1;
                #pragma unroll
                for (int jj = 0; jj < 4; ++jj) {
                    u0.u[jj] = pk2(fmaxf(a0[rb + 2 * jj], 0.f),
                                   fmaxf(a0[rb + 2 * jj + 1], 0.f));
                    u1.u[jj] = pk2(fmaxf(a1[rb + 2 * jj], 0.f),
                                   fmaxf(a1[rb + 2 * jj + 1], 0.f));
                }
                const bf16x8 hw = *reinterpret_cast<const bf16x8*>(
                    hawb + (2 * mt + t) * 128 + hoff);
                hacc0 = MFMA(hw, u0.v, hacc0, 0, 0, 0);
                hacc1 = MFMA(hw, u1.v, hacc1, 0, 0, 0);
            }
        }

        // ---- per-ray tail: select + bias + dir partial + sigmoid -----------
        const float hv0 = hi ? hacc1[0] : hacc0[0];
        const float hv1 = hi ? hacc1[1] : hacc0[1];
        const float hv2 = hi ? hacc1[2] : hacc0[2];
        const float hv3 = hi ? hacc1[3] : hacc0[3];

        const float sig = hv0 + sb;
        float cr  = hv1 + cb0 + crd;
        float cg  = hv2 + cb1 + cgd;
        float cbl = hv3 + cb2 + cbd;

        cr  = 1.0f / (1.0f + __expf(-cr));
        cg  = 1.0f / (1.0f + __expf(-cg));
        cbl = 1.0f / (1.0f + __expf(-cbl));

        out[ray] = sig;
        float3 rgbv; rgbv.x = cr; rgbv.y = cg; rgbv.z = cbl;
        *reinterpret_cast<float3*>(rgbout + (long)ray * 3) = rgbv;

        Pn = Pn2; Dc = Dn; Dn = Dn2;
    }
}

extern "C" void kernel_launch(void* const* d_in, const int* in_sizes, int n_in,
                              void* d_out, int out_size, void* d_ws, size_t ws_size,
                              hipStream_t stream) {
    const float* pos    = (const float*)d_in[0];
    const float* dirs   = (const float*)d_in[1];
    const float* params = (const float*)d_in[2];
    float* out = (float*)d_out;

    dim3 grid(1024);   // 16 blocks/batch x 64 batches (XCD-swizzled in-kernel)
    dim3 block(256);
    nerf_mfma_kernel<<<grid, block, 0, stream>>>(pos, dirs, params, out);
}